// Round 1
// baseline (1783.063 us; speedup 1.0000x reference)
//
#include <hip/hip_runtime.h>
#include <cstdint>

#define IN_DIM 128
#define HID 64

__device__ __forceinline__ float lrelu(float z) { return z > 0.f ? z : 0.2f * z; }

// ---------------- CSR construction ----------------

__global__ void k_hist(const int* __restrict__ dst, int E, int* __restrict__ counts) {
  int i = blockIdx.x * blockDim.x + threadIdx.x;
  int stride = gridDim.x * blockDim.x;
  for (; i < E; i += stride) atomicAdd(&counts[dst[i]], 1);
}

__global__ __launch_bounds__(1024) void k_scan1(const int* __restrict__ counts,
                                                int* __restrict__ offs,
                                                int* __restrict__ bsums, int n) {
  __shared__ int tmp[1024];
  int t = threadIdx.x;
  int gid = blockIdx.x * 1024 + t;
  int v = (gid < n) ? counts[gid] : 0;
  tmp[t] = v;
  __syncthreads();
  for (int off = 1; off < 1024; off <<= 1) {
    int u = (t >= off) ? tmp[t - off] : 0;
    __syncthreads();
    tmp[t] += u;
    __syncthreads();
  }
  if (gid < n) offs[gid] = tmp[t] - v;          // exclusive within block
  if (t == 1023) bsums[blockIdx.x] = tmp[t];    // block total
}

__global__ __launch_bounds__(128) void k_scan2(int* __restrict__ bsums, int nb) {
  __shared__ int tmp[128];
  int t = threadIdx.x;
  int v = (t < nb) ? bsums[t] : 0;
  tmp[t] = v;
  __syncthreads();
  for (int off = 1; off < 128; off <<= 1) {
    int u = (t >= off) ? tmp[t - off] : 0;
    __syncthreads();
    tmp[t] += u;
    __syncthreads();
  }
  if (t < nb) bsums[t] = tmp[t] - v;            // exclusive scan of block totals
}

__global__ __launch_bounds__(1024) void k_scan3(int* __restrict__ offs,
                                                const int* __restrict__ bsums,
                                                int* __restrict__ cursor, int n) {
  int gid = blockIdx.x * 1024 + threadIdx.x;
  if (gid < n) {
    int v = offs[gid] + bsums[blockIdx.x];
    offs[gid] = v;
    cursor[gid] = v;
  }
}

__global__ void k_scatter(const int* __restrict__ src, const int* __restrict__ dst, int E,
                          int* __restrict__ cursor, int* __restrict__ csr) {
  int i = blockIdx.x * blockDim.x + threadIdx.x;
  int stride = gridDim.x * blockDim.x;
  for (; i < E; i += stride) {
    int d = dst[i];
    int pos = atomicAdd(&cursor[d], 1);
    csr[pos] = src[i];
  }
}

// ---------------- fused GEMM + attention logits ----------------
// One wave handles R rows; lane = output column. W[k][c] loaded once per k,
// reused across R rows. ls = h . a_src, ld = h . a_dst via shuffle reduce.

template <int K, int R>
__global__ __launch_bounds__(256) void k_gemm_attn(
    const float* __restrict__ X, const float* __restrict__ W,
    const float* __restrict__ As, const float* __restrict__ Ad,
    float* __restrict__ H, float* __restrict__ LS, float* __restrict__ LD, int n) {
  int lane = threadIdx.x & 63;
  int wave = threadIdx.x >> 6;
  int row0 = (blockIdx.x * 4 + wave) * R;
  if (row0 >= n) return;
  float acc[R];
#pragma unroll
  for (int r = 0; r < R; ++r) acc[r] = 0.f;
  const float* xr = X + (size_t)row0 * K;
#pragma unroll 4
  for (int k = 0; k < K; ++k) {
    float wv = W[(k << 6) + lane];
#pragma unroll
    for (int r = 0; r < R; ++r) acc[r] = fmaf(xr[(size_t)r * K + k], wv, acc[r]);
  }
  float as = As[lane], ad = Ad[lane];
#pragma unroll
  for (int r = 0; r < R; ++r) {
    int row = row0 + r;
    H[((size_t)row << 6) | lane] = acc[r];
    float vs = acc[r] * as;
    float vd = acc[r] * ad;
#pragma unroll
    for (int off = 32; off; off >>= 1) {
      vs += __shfl_xor(vs, off);
      vd += __shfl_xor(vd, off);
    }
    if (lane == 0) { LS[row] = vs; LD[row] = vd; }
  }
}

// ---------------- per-node softmax aggregation ----------------
// One wave per destination node, lane = feature column.
// out[d] = relu( (sum_j exp(e_j - m) * h[src_j]) / (sum_j exp(e_j - m)) + b )
// Self-loop (src = dst) handled implicitly (not in CSR).

__global__ __launch_bounds__(256) void k_aggregate(
    const float* __restrict__ H, const float* __restrict__ LS, const float* __restrict__ LD,
    const int* __restrict__ csr, const int* __restrict__ offs, const int* __restrict__ counts,
    const float* __restrict__ b, float* __restrict__ Out, int n) {
  int lane = threadIdx.x & 63;
  int node = blockIdx.x * 4 + (threadIdx.x >> 6);
  if (node >= n) return;
  int start = offs[node];
  int deg = counts[node];
  float ldv = LD[node];
  float e_self = lrelu(LS[node] + ldv);
  // pass 1: max over neighborhood (lane-strided) + self loop
  float lmax = e_self;
  for (int j = lane; j < deg; j += 64) {
    int s = csr[start + j];
    lmax = fmaxf(lmax, lrelu(LS[s] + ldv));
  }
#pragma unroll
  for (int off = 32; off; off >>= 1) lmax = fmaxf(lmax, __shfl_xor(lmax, off));
  float m = lmax;
  // pass 2: weighted accumulation
  float wself = expf(e_self - m);
  float ssum = wself;
  float acc = wself * H[((size_t)node << 6) | lane];
  for (int j = 0; j < deg; ++j) {
    int s = csr[start + j];
    float w = expf(lrelu(LS[s] + ldv) - m);
    ssum += w;
    acc = fmaf(w, H[((size_t)s << 6) | lane], acc);
  }
  Out[((size_t)node << 6) | lane] = fmaxf(acc / ssum + b[lane], 0.f);
}

// ---------------- final log_softmax over 64 features ----------------

__global__ __launch_bounds__(256) void k_logsoftmax(const float* __restrict__ H,
                                                    float* __restrict__ Out, int n) {
  int lane = threadIdx.x & 63;
  int node = blockIdx.x * 4 + (threadIdx.x >> 6);
  if (node >= n) return;
  float v = H[((size_t)node << 6) | lane];
  float mx = v;
#pragma unroll
  for (int off = 32; off; off >>= 1) mx = fmaxf(mx, __shfl_xor(mx, off));
  float ex = expf(v - mx);
#pragma unroll
  for (int off = 32; off; off >>= 1) ex += __shfl_xor(ex, off);
  Out[((size_t)node << 6) | lane] = v - mx - logf(ex);
}

// ---------------- launcher ----------------

extern "C" void kernel_launch(void* const* d_in, const int* in_sizes, int n_in,
                              void* d_out, int out_size, void* d_ws, size_t ws_size,
                              hipStream_t stream) {
  const float* x = (const float*)d_in[0];
  const int* ei = (const int*)d_in[1];
  const int N = in_sizes[0] / IN_DIM;       // 100000
  const int E = in_sizes[1] / 2;            // 1600000
  const int* src = ei;
  const int* dst = ei + E;

  const float *W[6], *As[6], *Ad[6], *Bb[6];
  for (int i = 0; i < 6; ++i) {
    W[i]  = (const float*)d_in[3 + 4 * i];
    As[i] = (const float*)d_in[4 + 4 * i];
    Ad[i] = (const float*)d_in[5 + 4 * i];
    Bb[i] = (const float*)d_in[6 + 4 * i];
  }

  // workspace carve-out
  char* p = (char*)d_ws;
  auto alloc = [&](size_t bytes) -> void* {
    void* r = (void*)p;
    p += (bytes + 255) & ~(size_t)255;
    return r;
  };
  int* counts  = (int*)alloc((size_t)N * 4);
  int* offs    = (int*)alloc((size_t)N * 4);
  int* cursor  = (int*)alloc((size_t)N * 4);
  int* bsums   = (int*)alloc(512);
  int* csr     = (int*)alloc((size_t)E * 4);
  float* ls    = (float*)alloc((size_t)N * 4);
  float* ld    = (float*)alloc((size_t)N * 4);
  float* htmp  = (float*)alloc((size_t)N * HID * 4);
  float* F0    = (float*)alloc((size_t)N * HID * 4);
  float* F1    = (float*)d_out;   // layer 2/4/6 outputs live in d_out

  // ---- CSR build (once per call) ----
  hipMemsetAsync(counts, 0, (size_t)N * 4, stream);
  k_hist<<<2048, 256, 0, stream>>>(dst, E, counts);
  int nb = (N + 1023) / 1024;               // 98 (<=128)
  k_scan1<<<nb, 1024, 0, stream>>>(counts, offs, bsums, N);
  k_scan2<<<1, 128, 0, stream>>>(bsums, nb);
  k_scan3<<<nb, 1024, 0, stream>>>(offs, bsums, cursor, N);
  k_scatter<<<2048, 256, 0, stream>>>(src, dst, E, cursor, csr);

  // ---- 6 GAT layers ----
  const int R = 8;
  int gemm_grid = (N + 4 * R - 1) / (4 * R);    // 3125
  int node_grid = (N + 3) / 4;                  // 25000
  const float* fin = x;
  float* fbuf[2] = {F0, F1};
  for (int L = 0; L < 6; ++L) {
    if (L == 0)
      k_gemm_attn<IN_DIM, R><<<gemm_grid, 256, 0, stream>>>(fin, W[L], As[L], Ad[L],
                                                            htmp, ls, ld, N);
    else
      k_gemm_attn<HID, R><<<gemm_grid, 256, 0, stream>>>(fin, W[L], As[L], Ad[L],
                                                         htmp, ls, ld, N);
    float* fout = fbuf[L & 1];
    k_aggregate<<<node_grid, 256, 0, stream>>>(htmp, ls, ld, csr, offs, counts,
                                               Bb[L], fout, N);
    fin = fout;
  }

  // final log_softmax (in place on d_out)
  k_logsoftmax<<<node_grid, 256, 0, stream>>>(F1, (float*)d_out, N);
}

// Round 2
// 1328.630 us; speedup vs baseline: 1.3420x; 1.3420x over previous
//
#include <hip/hip_runtime.h>
#include <cstdint>

#define IN_DIM 128
#define HID 64

__device__ __forceinline__ float lrelu(float z) { return z > 0.f ? z : 0.2f * z; }

__device__ __forceinline__ float bcast(float v, int l) {
  return __int_as_float(__builtin_amdgcn_readlane(__float_as_int(v), l));
}

// ---------------- CSR construction ----------------

__global__ void k_hist(const int* __restrict__ dst, int E, int* __restrict__ counts) {
  int i = blockIdx.x * blockDim.x + threadIdx.x;
  int stride = gridDim.x * blockDim.x;
  for (; i < E; i += stride) atomicAdd(&counts[dst[i]], 1);
}

__global__ __launch_bounds__(1024) void k_scan1(const int* __restrict__ counts,
                                                int* __restrict__ offs,
                                                int* __restrict__ bsums, int n) {
  __shared__ int tmp[1024];
  int t = threadIdx.x;
  int gid = blockIdx.x * 1024 + t;
  int v = (gid < n) ? counts[gid] : 0;
  tmp[t] = v;
  __syncthreads();
  for (int off = 1; off < 1024; off <<= 1) {
    int u = (t >= off) ? tmp[t - off] : 0;
    __syncthreads();
    tmp[t] += u;
    __syncthreads();
  }
  if (gid < n) offs[gid] = tmp[t] - v;          // exclusive within block
  if (t == 1023) bsums[blockIdx.x] = tmp[t];    // block total
}

__global__ __launch_bounds__(128) void k_scan2(int* __restrict__ bsums, int nb) {
  __shared__ int tmp[128];
  int t = threadIdx.x;
  int v = (t < nb) ? bsums[t] : 0;
  tmp[t] = v;
  __syncthreads();
  for (int off = 1; off < 128; off <<= 1) {
    int u = (t >= off) ? tmp[t - off] : 0;
    __syncthreads();
    tmp[t] += u;
    __syncthreads();
  }
  if (t < nb) bsums[t] = tmp[t] - v;            // exclusive scan of block totals
}

__global__ __launch_bounds__(1024) void k_scan3(int* __restrict__ offs,
                                                const int* __restrict__ bsums,
                                                int* __restrict__ cursor, int n) {
  int gid = blockIdx.x * 1024 + threadIdx.x;
  if (gid < n) {
    int v = offs[gid] + bsums[blockIdx.x];
    offs[gid] = v;
    cursor[gid] = v;
  }
}

__global__ void k_scatter(const int* __restrict__ src, const int* __restrict__ dst, int E,
                          int* __restrict__ cursor, int* __restrict__ csr) {
  int i = blockIdx.x * blockDim.x + threadIdx.x;
  int stride = gridDim.x * blockDim.x;
  for (; i < E; i += stride) {
    int d = dst[i];
    int pos = atomicAdd(&cursor[d], 1);
    csr[pos] = src[i];
  }
}

// ---------------- fused GEMM + attention logits ----------------
// One wave handles R rows; lane = output column. W column held in 64 VGPRs,
// X row loaded coalesced then broadcast per-k via v_readlane (no memory op).

template <int K, int R>
__global__ __launch_bounds__(256) void k_gemm_attn(
    const float* __restrict__ X, const float* __restrict__ W,
    const float* __restrict__ As, const float* __restrict__ Ad,
    float* __restrict__ H, float* __restrict__ LS, float* __restrict__ LD, int n) {
  int lane = threadIdx.x & 63;
  int wave = threadIdx.x >> 6;
  int row0 = (blockIdx.x * 4 + wave) * R;
  if (row0 >= n) return;
  float acc[R];
#pragma unroll
  for (int r = 0; r < R; ++r) acc[r] = 0.f;

  for (int k0 = 0; k0 < K; k0 += 64) {
    float wreg[64];
#pragma unroll
    for (int kk = 0; kk < 64; ++kk) wreg[kk] = W[(size_t)(k0 + kk) * 64 + lane];
    float xv[R];
#pragma unroll
    for (int r = 0; r < R; ++r) {
      int row = row0 + r;
      if (row >= n) row = n - 1;                 // clamp (loads only)
      xv[r] = X[(size_t)row * K + k0 + lane];
    }
#pragma unroll
    for (int kk = 0; kk < 64; ++kk) {
#pragma unroll
      for (int r = 0; r < R; ++r)
        acc[r] = fmaf(bcast(xv[r], kk), wreg[kk], acc[r]);
    }
  }

  float as = As[lane], ad = Ad[lane];
#pragma unroll
  for (int r = 0; r < R; ++r) {
    int row = row0 + r;
    if (row >= n) break;
    H[((size_t)row << 6) | lane] = acc[r];
    float vs = acc[r] * as;
    float vd = acc[r] * ad;
#pragma unroll
    for (int off = 32; off; off >>= 1) {
      vs += __shfl_xor(vs, off);
      vd += __shfl_xor(vd, off);
    }
    if (lane == 0) { LS[row] = vs; LD[row] = vd; }
  }
}

// ---------------- per-node softmax aggregation (online, single pass) -------
// One wave per destination node, lane = feature column.
// Chunk of 64 edges: lanes compute e/exp in parallel; chunk-max + rescale;
// then broadcast inner loop (shfl from registers) for the weighted H gather.

__global__ __launch_bounds__(256) void k_aggregate(
    const float* __restrict__ H, const float* __restrict__ LS, const float* __restrict__ LD,
    const int* __restrict__ csr, const int* __restrict__ offs, const int* __restrict__ counts,
    const float* __restrict__ b, float* __restrict__ Out, int n) {
  int lane = threadIdx.x & 63;
  int node = blockIdx.x * 4 + (threadIdx.x >> 6);
  if (node >= n) return;
  int start = offs[node];
  int deg = counts[node];
  float ldv = LD[node];
  float m = lrelu(LS[node] + ldv);                     // e_self (running max)
  float acc = H[((size_t)node << 6) | lane];           // self contribution, w=1
  float ssum_l = (lane == 0) ? 1.f : 0.f;              // per-lane partial denom

  for (int c = 0; c < deg; c += 64) {
    int j = c + lane;
    bool valid = j < deg;
    int sidx = csr[start + (valid ? j : 0)];
    float e = valid ? lrelu(LS[sidx] + ldv) : -1e30f;
    float cm = e;
#pragma unroll
    for (int off = 32; off; off >>= 1) cm = fmaxf(cm, __shfl_xor(cm, off));
    if (cm > m) {
      float scale = __expf(m - cm);
      acc *= scale;
      ssum_l *= scale;
      m = cm;
    }
    float w = valid ? __expf(e - m) : 0.f;
    ssum_l += w;
    int nn = min(64, deg - c);
    for (int jj = 0; jj < nn; ++jj) {
      float wj = __shfl(w, jj);
      int sj = __shfl(sidx, jj);
      acc = fmaf(wj, H[((size_t)sj << 6) | lane], acc);
    }
  }
  float ssum = ssum_l;
#pragma unroll
  for (int off = 32; off; off >>= 1) ssum += __shfl_xor(ssum, off);
  Out[((size_t)node << 6) | lane] = fmaxf(acc / ssum + b[lane], 0.f);
}

// ---------------- final log_softmax over 64 features ----------------

__global__ __launch_bounds__(256) void k_logsoftmax(const float* __restrict__ H,
                                                    float* __restrict__ Out, int n) {
  int lane = threadIdx.x & 63;
  int node = blockIdx.x * 4 + (threadIdx.x >> 6);
  if (node >= n) return;
  float v = H[((size_t)node << 6) | lane];
  float mx = v;
#pragma unroll
  for (int off = 32; off; off >>= 1) mx = fmaxf(mx, __shfl_xor(mx, off));
  float ex = __expf(v - mx);
#pragma unroll
  for (int off = 32; off; off >>= 1) ex += __shfl_xor(ex, off);
  Out[((size_t)node << 6) | lane] = v - mx - logf(ex);
}

// ---------------- launcher ----------------

extern "C" void kernel_launch(void* const* d_in, const int* in_sizes, int n_in,
                              void* d_out, int out_size, void* d_ws, size_t ws_size,
                              hipStream_t stream) {
  const float* x = (const float*)d_in[0];
  const int* ei = (const int*)d_in[1];
  const int N = in_sizes[0] / IN_DIM;       // 100000
  const int E = in_sizes[1] / 2;            // 1600000
  const int* src = ei;
  const int* dst = ei + E;

  const float *W[6], *As[6], *Ad[6], *Bb[6];
  for (int i = 0; i < 6; ++i) {
    W[i]  = (const float*)d_in[3 + 4 * i];
    As[i] = (const float*)d_in[4 + 4 * i];
    Ad[i] = (const float*)d_in[5 + 4 * i];
    Bb[i] = (const float*)d_in[6 + 4 * i];
  }

  // workspace carve-out
  char* p = (char*)d_ws;
  auto alloc = [&](size_t bytes) -> void* {
    void* r = (void*)p;
    p += (bytes + 255) & ~(size_t)255;
    return r;
  };
  int* counts  = (int*)alloc((size_t)N * 4);
  int* offs    = (int*)alloc((size_t)N * 4);
  int* cursor  = (int*)alloc((size_t)N * 4);
  int* bsums   = (int*)alloc(512);
  int* csr     = (int*)alloc((size_t)E * 4);
  float* ls    = (float*)alloc((size_t)N * 4);
  float* ld    = (float*)alloc((size_t)N * 4);
  float* htmp  = (float*)alloc((size_t)N * HID * 4);
  float* F0    = (float*)alloc((size_t)N * HID * 4);
  float* F1    = (float*)d_out;   // layer 2/4/6 outputs live in d_out

  // ---- CSR build (once per call) ----
  hipMemsetAsync(counts, 0, (size_t)N * 4, stream);
  k_hist<<<2048, 256, 0, stream>>>(dst, E, counts);
  int nb = (N + 1023) / 1024;               // 98 (<=128)
  k_scan1<<<nb, 1024, 0, stream>>>(counts, offs, bsums, N);
  k_scan2<<<1, 128, 0, stream>>>(bsums, nb);
  k_scan3<<<nb, 1024, 0, stream>>>(offs, bsums, cursor, N);
  k_scatter<<<2048, 256, 0, stream>>>(src, dst, E, cursor, csr);

  // ---- 6 GAT layers ----
  const int R = 8;
  int gemm_grid = (N + 4 * R - 1) / (4 * R);    // 3125
  int node_grid = (N + 3) / 4;                  // 25000
  const float* fin = x;
  float* fbuf[2] = {F0, F1};
  for (int L = 0; L < 6; ++L) {
    if (L == 0)
      k_gemm_attn<IN_DIM, R><<<gemm_grid, 256, 0, stream>>>(fin, W[L], As[L], Ad[L],
                                                            htmp, ls, ld, N);
    else
      k_gemm_attn<HID, R><<<gemm_grid, 256, 0, stream>>>(fin, W[L], As[L], Ad[L],
                                                         htmp, ls, ld, N);
    float* fout = fbuf[L & 1];
    k_aggregate<<<node_grid, 256, 0, stream>>>(htmp, ls, ld, csr, offs, counts,
                                               Bb[L], fout, N);
    fin = fout;
  }

  // final log_softmax (in place on d_out)
  k_logsoftmax<<<node_grid, 256, 0, stream>>>(F1, (float*)d_out, N);
}

// Round 3
// 1039.813 us; speedup vs baseline: 1.7148x; 1.2778x over previous
//
#include <hip/hip_runtime.h>
#include <cstdint>

#define IN_DIM 128
#define HID 64
#define BK 512              // nodes per bucket (power of 2)
#define BKSH 9
#define CH 4096             // edges per chunk
#define CAP 9216            // LDS csr staging capacity (mean 8192 + 11 sigma)

__device__ __forceinline__ float lrelu(float z) { return z > 0.f ? z : 0.2f * z; }

__device__ __forceinline__ float bcast(float v, int l) {
  return __int_as_float(__builtin_amdgcn_readlane(__float_as_int(v), l));
}

// ---------------- CSR construction (bucket counting sort) ----------------

__global__ __launch_bounds__(256) void k_bucket_hist(const int* __restrict__ dst, int E,
                                                     int* __restrict__ gcnt, int NB) {
  __shared__ int h[256];
  int tid = threadIdx.x;
  if (tid < NB) h[tid] = 0;
  __syncthreads();
  int cbase = blockIdx.x * CH;
  int cend = min(cbase + CH, E);
  for (int i = cbase + tid; i < cend; i += 256) atomicAdd(&h[dst[i] >> BKSH], 1);
  __syncthreads();
  if (tid < NB && h[tid]) atomicAdd(&gcnt[tid], h[tid]);
}

// single block: exclusive scan of bucket counts (NB <= 256)
__global__ __launch_bounds__(256) void k_bucket_scan(const int* __restrict__ gcnt,
                                                     int* __restrict__ bbase,
                                                     int* __restrict__ bcur, int NB) {
  __shared__ int sc[256];
  int tid = threadIdx.x;
  int v = (tid < NB) ? gcnt[tid] : 0;
  sc[tid] = v;
  __syncthreads();
  for (int off = 1; off < 256; off <<= 1) {
    int u = (tid >= off) ? sc[tid - off] : 0;
    __syncthreads();
    sc[tid] += u;
    __syncthreads();
  }
  int excl = sc[tid] - v;
  if (tid < NB) { bbase[tid] = excl; bcur[tid] = excl; }
  if (tid == 255) bbase[NB] = sc[255];   // total = E
}

__global__ __launch_bounds__(256) void k_bucket_scatter(
    const int* __restrict__ src, const int* __restrict__ dst, int E,
    int* __restrict__ bcur, uint32_t* __restrict__ staged, int NB) {
  __shared__ int h[256];
  __shared__ int base[256];
  int tid = threadIdx.x;
  if (tid < NB) h[tid] = 0;
  __syncthreads();
  int cbase = blockIdx.x * CH;
  int cend = min(cbase + CH, E);
  uint32_t pay[16];
  int bk[16], rk[16];
#pragma unroll
  for (int k = 0; k < 16; ++k) {
    int i = cbase + tid + (k << 8);
    bool valid = i < cend;
    int d = valid ? dst[i] : 0;
    int s = valid ? src[i] : 0;
    int b = d >> BKSH;
    bk[k] = valid ? b : -1;
    rk[k] = valid ? atomicAdd(&h[b], 1) : 0;
    pay[k] = (uint32_t)s | ((uint32_t)(d & (BK - 1)) << 20);
  }
  __syncthreads();
  if (tid < NB && h[tid]) base[tid] = atomicAdd(&bcur[tid], h[tid]);
  __syncthreads();
#pragma unroll
  for (int k = 0; k < 16; ++k)
    if (bk[k] >= 0) staged[base[bk[k]] + rk[k]] = pay[k];
}

// one block per bucket: build node offsets/counts + coalesced csr write
__global__ __launch_bounds__(256) void k_csr_final(
    const uint32_t* __restrict__ staged, const int* __restrict__ bbase,
    int* __restrict__ offs, int* __restrict__ counts, int* __restrict__ csr, int n) {
  __shared__ int nhist[BK];
  __shared__ int sc[BK];
  __shared__ int ncur[BK];
  __shared__ int csrloc[CAP];
  int b = blockIdx.x, tid = threadIdx.x;
  int bb = bbase[b], be = bbase[b + 1];
  int cnt = be - bb;
  for (int t = tid; t < BK; t += 256) nhist[t] = 0;
  __syncthreads();
  for (int k = tid; k < cnt; k += 256) atomicAdd(&nhist[staged[bb + k] >> 20], 1);
  __syncthreads();
  // inclusive scan of nhist (512 elems, 2 per thread)
  sc[tid] = nhist[tid];
  sc[tid + 256] = nhist[tid + 256];
  __syncthreads();
  for (int off = 1; off < BK; off <<= 1) {
    int a0 = (tid >= off) ? sc[tid - off] : 0;
    int a1 = (tid + 256 >= off) ? sc[tid + 256 - off] : 0;
    __syncthreads();
    sc[tid] += a0;
    sc[tid + 256] += a1;
    __syncthreads();
  }
  int node0 = b << BKSH;
  for (int t = tid; t < BK; t += 256) {
    int excl = sc[t] - nhist[t];
    int node = node0 + t;
    if (node < n) { counts[node] = nhist[t]; offs[node] = bb + excl; }
    ncur[t] = excl;
  }
  __syncthreads();
  for (int k = tid; k < cnt; k += 256) {
    uint32_t u = staged[bb + k];
    int dl = u >> 20;
    int s = (int)(u & 0xFFFFFu);
    int pos = atomicAdd(&ncur[dl], 1);
    if (pos < CAP) csrloc[pos] = s;
    else csr[bb + pos] = s;        // overflow fallback (correct, rare)
  }
  __syncthreads();
  int lim = min(cnt, CAP);
  for (int k = tid; k < lim; k += 256) csr[bb + k] = csrloc[k];
}

// ---------------- fused GEMM + attention logits ----------------

template <int K, int R>
__global__ __launch_bounds__(256) void k_gemm_attn(
    const float* __restrict__ X, const float* __restrict__ W,
    const float* __restrict__ As, const float* __restrict__ Ad,
    float* __restrict__ H, float* __restrict__ LS, float* __restrict__ LD, int n) {
  int lane = threadIdx.x & 63;
  int wave = threadIdx.x >> 6;
  int row0 = (blockIdx.x * 4 + wave) * R;
  if (row0 >= n) return;
  float acc[R];
#pragma unroll
  for (int r = 0; r < R; ++r) acc[r] = 0.f;

  for (int k0 = 0; k0 < K; k0 += 64) {
    float wreg[64];
#pragma unroll
    for (int kk = 0; kk < 64; ++kk) wreg[kk] = W[(size_t)(k0 + kk) * 64 + lane];
    float xv[R];
#pragma unroll
    for (int r = 0; r < R; ++r) {
      int row = row0 + r;
      if (row >= n) row = n - 1;                 // clamp (loads only)
      xv[r] = X[(size_t)row * K + k0 + lane];
    }
#pragma unroll
    for (int kk = 0; kk < 64; ++kk) {
#pragma unroll
      for (int r = 0; r < R; ++r)
        acc[r] = fmaf(bcast(xv[r], kk), wreg[kk], acc[r]);
    }
  }

  float as = As[lane], ad = Ad[lane];
#pragma unroll
  for (int r = 0; r < R; ++r) {
    int row = row0 + r;
    if (row >= n) break;
    H[((size_t)row << 6) | lane] = acc[r];
    float vs = acc[r] * as;
    float vd = acc[r] * ad;
#pragma unroll
    for (int off = 32; off; off >>= 1) {
      vs += __shfl_xor(vs, off);
      vd += __shfl_xor(vd, off);
    }
    if (lane == 0) { LS[row] = vs; LD[row] = vd; }
  }
}

// ---------------- per-node softmax aggregation (online, single pass) -------
// LAST=true fuses the final log_softmax.

template <bool LAST>
__global__ __launch_bounds__(1024) void k_aggregate(
    const float* __restrict__ H, const float* __restrict__ LS, const float* __restrict__ LD,
    const int* __restrict__ csr, const int* __restrict__ offs, const int* __restrict__ counts,
    const float* __restrict__ b, float* __restrict__ Out, int n) {
  int lane = threadIdx.x & 63;
  int node = blockIdx.x * 16 + (threadIdx.x >> 6);
  if (node >= n) return;
  int start = offs[node];
  int deg = counts[node];
  float bias = b[lane];
  float ldv = LD[node];
  float m = lrelu(LS[node] + ldv);                     // e_self (running max)
  float acc = H[((size_t)node << 6) | lane];           // self contribution, w=1
  float ssum_l = (lane == 0) ? 1.f : 0.f;              // per-lane partial denom

  for (int c = 0; c < deg; c += 64) {
    int j = c + lane;
    bool valid = j < deg;
    int sidx = csr[start + (valid ? j : 0)];
    float e = valid ? lrelu(LS[sidx] + ldv) : -1e30f;
    float cm = e;
#pragma unroll
    for (int off = 32; off; off >>= 1) cm = fmaxf(cm, __shfl_xor(cm, off));
    if (cm > m) {
      float scale = __expf(m - cm);
      acc *= scale;
      ssum_l *= scale;
      m = cm;
    }
    float w = valid ? __expf(e - m) : 0.f;
    ssum_l += w;
    int nn = min(64, deg - c);
    int jj = 0;
    for (; jj + 8 <= nn; jj += 8) {
      float wv[8];
      int sv[8];
#pragma unroll
      for (int q = 0; q < 8; ++q) {
        wv[q] = __shfl(w, jj + q);
        sv[q] = __shfl(sidx, jj + q);
      }
      float hv[8];
#pragma unroll
      for (int q = 0; q < 8; ++q) hv[q] = H[((size_t)sv[q] << 6) | lane];
#pragma unroll
      for (int q = 0; q < 8; ++q) acc = fmaf(wv[q], hv[q], acc);
    }
    for (; jj < nn; ++jj) {
      float wj = __shfl(w, jj);
      int sj = __shfl(sidx, jj);
      acc = fmaf(wj, H[((size_t)sj << 6) | lane], acc);
    }
  }
  float ssum = ssum_l;
#pragma unroll
  for (int off = 32; off; off >>= 1) ssum += __shfl_xor(ssum, off);
  float v = fmaxf(acc / ssum + bias, 0.f);
  if (LAST) {
    float mx = v;
#pragma unroll
    for (int off = 32; off; off >>= 1) mx = fmaxf(mx, __shfl_xor(mx, off));
    float ex = __expf(v - mx);
#pragma unroll
    for (int off = 32; off; off >>= 1) ex += __shfl_xor(ex, off);
    v = v - mx - logf(ex);
  }
  Out[((size_t)node << 6) | lane] = v;
}

// ---------------- launcher ----------------

extern "C" void kernel_launch(void* const* d_in, const int* in_sizes, int n_in,
                              void* d_out, int out_size, void* d_ws, size_t ws_size,
                              hipStream_t stream) {
  const float* x = (const float*)d_in[0];
  const int* ei = (const int*)d_in[1];
  const int N = in_sizes[0] / IN_DIM;       // 100000
  const int E = in_sizes[1] / 2;            // 1600000
  const int* src = ei;
  const int* dst = ei + E;
  const int NB = (N + BK - 1) >> BKSH;      // 196

  const float *W[6], *As[6], *Ad[6], *Bb[6];
  for (int i = 0; i < 6; ++i) {
    W[i]  = (const float*)d_in[3 + 4 * i];
    As[i] = (const float*)d_in[4 + 4 * i];
    Ad[i] = (const float*)d_in[5 + 4 * i];
    Bb[i] = (const float*)d_in[6 + 4 * i];
  }

  // workspace carve-out
  char* p = (char*)d_ws;
  auto alloc = [&](size_t bytes) -> void* {
    void* r = (void*)p;
    p += (bytes + 255) & ~(size_t)255;
    return r;
  };
  int* counts  = (int*)alloc((size_t)N * 4);
  int* offs    = (int*)alloc((size_t)N * 4);
  int* gcnt    = (int*)alloc((size_t)NB * 4);
  int* bbase   = (int*)alloc((size_t)(NB + 1) * 4);
  int* bcur    = (int*)alloc((size_t)NB * 4);
  int* csr     = (int*)alloc((size_t)E * 4);
  float* ls    = (float*)alloc((size_t)N * 4);
  float* ld    = (float*)alloc((size_t)N * 4);
  float* htmp  = (float*)alloc((size_t)N * HID * 4);
  float* F0    = (float*)alloc((size_t)N * HID * 4);
  float* F1    = (float*)d_out;              // layer 2/4/6 outputs live in d_out
  uint32_t* staged = (uint32_t*)F0;          // alias: dead before first aggregate

  // ---- CSR build (bucket counting sort) ----
  int NC = (E + CH - 1) / CH;               // 391
  hipMemsetAsync(gcnt, 0, (size_t)NB * 4, stream);
  k_bucket_hist<<<NC, 256, 0, stream>>>(dst, E, gcnt, NB);
  k_bucket_scan<<<1, 256, 0, stream>>>(gcnt, bbase, bcur, NB);
  k_bucket_scatter<<<NC, 256, 0, stream>>>(src, dst, E, bcur, staged, NB);
  k_csr_final<<<NB, 256, 0, stream>>>(staged, bbase, offs, counts, csr, N);

  // ---- 6 GAT layers ----
  const int R = 8;
  int gemm_grid = (N + 4 * R - 1) / (4 * R);    // 3125
  int node_grid = (N + 15) / 16;                // 6250
  const float* fin = x;
  float* fbuf[2] = {F0, F1};
  for (int L = 0; L < 6; ++L) {
    if (L == 0)
      k_gemm_attn<IN_DIM, R><<<gemm_grid, 256, 0, stream>>>(fin, W[L], As[L], Ad[L],
                                                            htmp, ls, ld, N);
    else
      k_gemm_attn<HID, R><<<gemm_grid, 256, 0, stream>>>(fin, W[L], As[L], Ad[L],
                                                         htmp, ls, ld, N);
    float* fout = fbuf[L & 1];
    if (L == 5)
      k_aggregate<true><<<node_grid, 1024, 0, stream>>>(htmp, ls, ld, csr, offs, counts,
                                                        Bb[L], fout, N);
    else
      k_aggregate<false><<<node_grid, 1024, 0, stream>>>(htmp, ls, ld, csr, offs, counts,
                                                         Bb[L], fout, N);
    fin = fout;
  }
}

// Round 4
// 820.443 us; speedup vs baseline: 2.1733x; 1.2674x over previous
//
#include <hip/hip_runtime.h>
#include <hip/hip_bf16.h>
#include <cstdint>

#define IN_DIM 128
#define HID 64
#define BK 512              // nodes per bucket (power of 2)
#define BKSH 9
#define CH 4096             // edges per chunk
#define CAP 9216            // LDS csr staging capacity

__device__ __forceinline__ float lrelu(float z) { return z > 0.f ? z : 0.2f * z; }

__device__ __forceinline__ float bcast(float v, int l) {
  return __int_as_float(__builtin_amdgcn_readlane(__float_as_int(v), l));
}

__device__ __forceinline__ float bf2f(uint16_t u) {
  return __uint_as_float((uint32_t)u << 16);
}

// ---------------- CSR construction (bucket counting sort) ----------------

__global__ __launch_bounds__(256) void k_bucket_hist(const int* __restrict__ dst, int E,
                                                     int* __restrict__ gcnt, int NB) {
  __shared__ int h[256];
  int tid = threadIdx.x;
  if (tid < NB) h[tid] = 0;
  __syncthreads();
  int cbase = blockIdx.x * CH;
  int cend = min(cbase + CH, E);
  for (int i = cbase + tid; i < cend; i += 256) atomicAdd(&h[dst[i] >> BKSH], 1);
  __syncthreads();
  if (tid < NB && h[tid]) atomicAdd(&gcnt[tid], h[tid]);
}

__global__ __launch_bounds__(256) void k_bucket_scan(const int* __restrict__ gcnt,
                                                     int* __restrict__ bbase,
                                                     int* __restrict__ bcur, int NB) {
  __shared__ int sc[256];
  int tid = threadIdx.x;
  int v = (tid < NB) ? gcnt[tid] : 0;
  sc[tid] = v;
  __syncthreads();
  for (int off = 1; off < 256; off <<= 1) {
    int u = (tid >= off) ? sc[tid - off] : 0;
    __syncthreads();
    sc[tid] += u;
    __syncthreads();
  }
  int excl = sc[tid] - v;
  if (tid < NB) { bbase[tid] = excl; bcur[tid] = excl; }
  if (tid == 255) bbase[NB] = sc[255];
}

__global__ __launch_bounds__(256) void k_bucket_scatter(
    const int* __restrict__ src, const int* __restrict__ dst, int E,
    int* __restrict__ bcur, uint32_t* __restrict__ staged, int NB) {
  __shared__ int h[256];
  __shared__ int base[256];
  int tid = threadIdx.x;
  if (tid < NB) h[tid] = 0;
  __syncthreads();
  int cbase = blockIdx.x * CH;
  int cend = min(cbase + CH, E);
  uint32_t pay[16];
  int bk[16], rk[16];
#pragma unroll
  for (int k = 0; k < 16; ++k) {
    int i = cbase + tid + (k << 8);
    bool valid = i < cend;
    int d = valid ? dst[i] : 0;
    int s = valid ? src[i] : 0;
    int b = d >> BKSH;
    bk[k] = valid ? b : -1;
    rk[k] = valid ? atomicAdd(&h[b], 1) : 0;
    pay[k] = (uint32_t)s | ((uint32_t)(d & (BK - 1)) << 20);
  }
  __syncthreads();
  if (tid < NB && h[tid]) base[tid] = atomicAdd(&bcur[tid], h[tid]);
  __syncthreads();
#pragma unroll
  for (int k = 0; k < 16; ++k)
    if (bk[k] >= 0) staged[base[bk[k]] + rk[k]] = pay[k];
}

__global__ __launch_bounds__(256) void k_csr_final(
    const uint32_t* __restrict__ staged, const int* __restrict__ bbase,
    int* __restrict__ offs, int* __restrict__ counts, int* __restrict__ csr, int n) {
  __shared__ int nhist[BK];
  __shared__ int sc[BK];
  __shared__ int ncur[BK];
  __shared__ int csrloc[CAP];
  int b = blockIdx.x, tid = threadIdx.x;
  int bb = bbase[b], be = bbase[b + 1];
  int cnt = be - bb;
  for (int t = tid; t < BK; t += 256) nhist[t] = 0;
  __syncthreads();
  for (int k = tid; k < cnt; k += 256) atomicAdd(&nhist[staged[bb + k] >> 20], 1);
  __syncthreads();
  sc[tid] = nhist[tid];
  sc[tid + 256] = nhist[tid + 256];
  __syncthreads();
  for (int off = 1; off < BK; off <<= 1) {
    int a0 = (tid >= off) ? sc[tid - off] : 0;
    int a1 = (tid + 256 >= off) ? sc[tid + 256 - off] : 0;
    __syncthreads();
    sc[tid] += a0;
    sc[tid + 256] += a1;
    __syncthreads();
  }
  int node0 = b << BKSH;
  for (int t = tid; t < BK; t += 256) {
    int excl = sc[t] - nhist[t];
    int node = node0 + t;
    if (node < n) { counts[node] = nhist[t]; offs[node] = bb + excl; }
    ncur[t] = excl;
  }
  __syncthreads();
  for (int k = tid; k < cnt; k += 256) {
    uint32_t u = staged[bb + k];
    int dl = u >> 20;
    int s = (int)(u & 0xFFFFFu);
    int pos = atomicAdd(&ncur[dl], 1);
    if (pos < CAP) csrloc[pos] = s;
    else csr[bb + pos] = s;
  }
  __syncthreads();
  int lim = min(cnt, CAP);
  for (int k = tid; k < lim; k += 256) csr[bb + k] = csrloc[k];
}

// ---------------- fused GEMM + attention logits (H written as bf16) -------

template <int K, int R>
__global__ __launch_bounds__(256) void k_gemm_attn(
    const float* __restrict__ X, const float* __restrict__ W,
    const float* __restrict__ As, const float* __restrict__ Ad,
    uint16_t* __restrict__ H2, float* __restrict__ LS, float* __restrict__ LD, int n) {
  int lane = threadIdx.x & 63;
  int wave = threadIdx.x >> 6;
  int row0 = (blockIdx.x * 4 + wave) * R;
  if (row0 >= n) return;
  float acc[R];
#pragma unroll
  for (int r = 0; r < R; ++r) acc[r] = 0.f;

  for (int k0 = 0; k0 < K; k0 += 64) {
    float wreg[64];
#pragma unroll
    for (int kk = 0; kk < 64; ++kk) wreg[kk] = W[(size_t)(k0 + kk) * 64 + lane];
    float xv[R];
#pragma unroll
    for (int r = 0; r < R; ++r) {
      int row = row0 + r;
      if (row >= n) row = n - 1;                 // clamp (loads only)
      xv[r] = X[(size_t)row * K + k0 + lane];
    }
#pragma unroll
    for (int kk = 0; kk < 64; ++kk) {
#pragma unroll
      for (int r = 0; r < R; ++r)
        acc[r] = fmaf(bcast(xv[r], kk), wreg[kk], acc[r]);
    }
  }

  float as = As[lane], ad = Ad[lane];
#pragma unroll
  for (int r = 0; r < R; ++r) {
    int row = row0 + r;
    if (row >= n) break;
    __hip_bfloat16 hb = __float2bfloat16(acc[r]);    // RNE
    H2[((size_t)row << 6) | lane] = *(uint16_t*)&hb;
    float vs = acc[r] * as;
    float vd = acc[r] * ad;
#pragma unroll
    for (int off = 32; off; off >>= 1) {
      vs += __shfl_xor(vs, off);
      vd += __shfl_xor(vd, off);
    }
    if (lane == 0) { LS[row] = vs; LD[row] = vd; }
  }
}

// ---------------- per-node softmax aggregation (online, bf16 pair-gather) --
// One wave per node. Edge phase: 64 lanes compute e/exp in parallel.
// Gather phase: lanes 0-31 serve edge j (group g=0), lanes 32-63 edge j+1;
// each lane loads ushort2 = 2 bf16 features of its group's source row.
// acc0/acc1 hold features (2q, 2q+1); cross-group combine via shfl_xor(32).

template <bool LAST>
__global__ __launch_bounds__(256) void k_aggregate(
    const uint16_t* __restrict__ H2, const float* __restrict__ LS, const float* __restrict__ LD,
    const int* __restrict__ csr, const int* __restrict__ offs, const int* __restrict__ counts,
    const float* __restrict__ b, float* __restrict__ Out, int n) {
  int lane = threadIdx.x & 63;
  int node = blockIdx.x * 4 + (threadIdx.x >> 6);
  if (node >= n) return;
  int q = lane & 31;
  int g = lane >> 5;
  int start = offs[node];
  int deg = counts[node];
  float2 bb = ((const float2*)b)[q];
  float ldv = LD[node];
  float m = lrelu(LS[node] + ldv);                 // e_self (running max)
  float ssum_l = (lane == 0) ? 1.f : 0.f;

  // self contribution (w=1), only group 0 accumulates it
  ushort2 us = *(const ushort2*)&H2[((size_t)node << 6) + 2 * q];
  float wself = (g == 0) ? 1.f : 0.f;
  float acc0 = wself * bf2f(us.x);
  float acc1 = wself * bf2f(us.y);

  for (int c = 0; c < deg; c += 64) {
    int j = c + lane;
    bool valid = j < deg;
    int sidx = csr[start + (valid ? j : 0)];
    float e = valid ? lrelu(LS[sidx] + ldv) : -1e30f;
    float cm = e;
#pragma unroll
    for (int off = 32; off; off >>= 1) cm = fmaxf(cm, __shfl_xor(cm, off));
    if (cm > m) {
      float scale = __expf(m - cm);
      acc0 *= scale; acc1 *= scale; ssum_l *= scale;
      m = cm;
    }
    float w = valid ? __expf(e - m) : 0.f;         // invalid lanes: w = 0
    ssum_l += w;
    int nn = min(64, deg - c);
    int jj = 0;
    for (; jj + 8 <= nn; jj += 8) {                // 4 edge-pairs per iter
      float wp[4]; int sp[4];
#pragma unroll
      for (int t = 0; t < 4; ++t) {
        int idx = jj + 2 * t + g;
        wp[t] = __shfl(w, idx);
        sp[t] = __shfl(sidx, idx);
      }
      ushort2 up[4];
#pragma unroll
      for (int t = 0; t < 4; ++t)
        up[t] = *(const ushort2*)&H2[((size_t)sp[t] << 6) + 2 * q];
#pragma unroll
      for (int t = 0; t < 4; ++t) {
        acc0 = fmaf(wp[t], bf2f(up[t].x), acc0);
        acc1 = fmaf(wp[t], bf2f(up[t].y), acc1);
      }
    }
    for (; jj < nn; jj += 2) {                     // residue pairs
      int idx = min(jj + g, 63);                   // overflow lane has w=0
      float wg = __shfl(w, idx);
      int sg = __shfl(sidx, idx);
      ushort2 u2 = *(const ushort2*)&H2[((size_t)sg << 6) + 2 * q];
      acc0 = fmaf(wg, bf2f(u2.x), acc0);
      acc1 = fmaf(wg, bf2f(u2.y), acc1);
    }
  }
  // cross-group combine + denominator
  acc0 += __shfl_xor(acc0, 32);
  acc1 += __shfl_xor(acc1, 32);
  float ssum = ssum_l;
#pragma unroll
  for (int off = 32; off; off >>= 1) ssum += __shfl_xor(ssum, off);
  float inv = 1.f / ssum;
  float v0 = fmaxf(fmaf(acc0, inv, bb.x), 0.f);
  float v1 = fmaxf(fmaf(acc1, inv, bb.y), 0.f);
  if (LAST) {
    float mx = fmaxf(v0, v1);
#pragma unroll
    for (int off = 32; off; off >>= 1) mx = fmaxf(mx, __shfl_xor(mx, off));
    float ex = __expf(v0 - mx) + __expf(v1 - mx);
#pragma unroll
    for (int off = 16; off; off >>= 1) ex += __shfl_xor(ex, off);  // within group
    float ls = mx + logf(ex);
    v0 -= ls; v1 -= ls;
  }
  if (g == 0)
    ((float2*)(Out + ((size_t)node << 6)))[q] = make_float2(v0, v1);
}

// ---------------- launcher ----------------

extern "C" void kernel_launch(void* const* d_in, const int* in_sizes, int n_in,
                              void* d_out, int out_size, void* d_ws, size_t ws_size,
                              hipStream_t stream) {
  const float* x = (const float*)d_in[0];
  const int* ei = (const int*)d_in[1];
  const int N = in_sizes[0] / IN_DIM;       // 100000
  const int E = in_sizes[1] / 2;            // 1600000
  const int* src = ei;
  const int* dst = ei + E;
  const int NB = (N + BK - 1) >> BKSH;      // 196

  const float *W[6], *As[6], *Ad[6], *Bb[6];
  for (int i = 0; i < 6; ++i) {
    W[i]  = (const float*)d_in[3 + 4 * i];
    As[i] = (const float*)d_in[4 + 4 * i];
    Ad[i] = (const float*)d_in[5 + 4 * i];
    Bb[i] = (const float*)d_in[6 + 4 * i];
  }

  char* p = (char*)d_ws;
  auto alloc = [&](size_t bytes) -> void* {
    void* r = (void*)p;
    p += (bytes + 255) & ~(size_t)255;
    return r;
  };
  int* counts  = (int*)alloc((size_t)N * 4);
  int* offs    = (int*)alloc((size_t)N * 4);
  int* gcnt    = (int*)alloc((size_t)NB * 4);
  int* bbase   = (int*)alloc((size_t)(NB + 1) * 4);
  int* bcur    = (int*)alloc((size_t)NB * 4);
  int* csr     = (int*)alloc((size_t)E * 4);
  float* ls    = (float*)alloc((size_t)N * 4);
  float* ld    = (float*)alloc((size_t)N * 4);
  uint16_t* h2 = (uint16_t*)alloc((size_t)N * HID * 2);
  float* F0    = (float*)alloc((size_t)N * HID * 4);
  float* F1    = (float*)d_out;
  uint32_t* staged = (uint32_t*)F0;          // alias: dead before first aggregate

  // ---- CSR build ----
  int NC = (E + CH - 1) / CH;
  hipMemsetAsync(gcnt, 0, (size_t)NB * 4, stream);
  k_bucket_hist<<<NC, 256, 0, stream>>>(dst, E, gcnt, NB);
  k_bucket_scan<<<1, 256, 0, stream>>>(gcnt, bbase, bcur, NB);
  k_bucket_scatter<<<NC, 256, 0, stream>>>(src, dst, E, bcur, staged, NB);
  k_csr_final<<<NB, 256, 0, stream>>>(staged, bbase, offs, counts, csr, N);

  // ---- 6 GAT layers ----
  const int R = 8;
  int gemm_grid = (N + 4 * R - 1) / (4 * R);    // 3125
  int node_grid = (N + 3) / 4;                  // 25000
  const float* fin = x;
  float* fbuf[2] = {F0, F1};
  for (int L = 0; L < 6; ++L) {
    if (L == 0)
      k_gemm_attn<IN_DIM, R><<<gemm_grid, 256, 0, stream>>>(fin, W[L], As[L], Ad[L],
                                                            h2, ls, ld, N);
    else
      k_gemm_attn<HID, R><<<gemm_grid, 256, 0, stream>>>(fin, W[L], As[L], Ad[L],
                                                         h2, ls, ld, N);
    float* fout = fbuf[L & 1];
    if (L == 5)
      k_aggregate<true><<<node_grid, 256, 0, stream>>>(h2, ls, ld, csr, offs, counts,
                                                       Bb[L], fout, N);
    else
      k_aggregate<false><<<node_grid, 256, 0, stream>>>(h2, ls, ld, csr, offs, counts,
                                                        Bb[L], fout, N);
    fin = fout;
  }
}

// Round 6
// 808.445 us; speedup vs baseline: 2.2055x; 1.0148x over previous
//
#include <hip/hip_runtime.h>
#include <hip/hip_bf16.h>
#include <cstdint>

#define IN_DIM 128
#define HID 64
#define BK 512              // nodes per bucket (power of 2)
#define BKSH 9
#define CH 4096             // edges per chunk
#define CAP 9216            // LDS csr staging capacity

__device__ __forceinline__ float lrelu(float z) { return z > 0.f ? z : 0.2f * z; }

__device__ __forceinline__ float bcast(float v, int l) {
  return __int_as_float(__builtin_amdgcn_readlane(__float_as_int(v), l));
}

__device__ __forceinline__ float bf2f(uint16_t u) {
  return __uint_as_float((uint32_t)u << 16);
}

// ---------------- CSR construction (bucket counting sort) ----------------

__global__ __launch_bounds__(256) void k_bucket_hist(const int* __restrict__ dst, int E,
                                                     int* __restrict__ gcnt, int NB) {
  __shared__ int h[256];
  int tid = threadIdx.x;
  if (tid < NB) h[tid] = 0;
  __syncthreads();
  int cbase = blockIdx.x * CH;
  int cend = min(cbase + CH, E);
  for (int i = cbase + tid; i < cend; i += 256) atomicAdd(&h[dst[i] >> BKSH], 1);
  __syncthreads();
  if (tid < NB && h[tid]) atomicAdd(&gcnt[tid], h[tid]);
}

__global__ __launch_bounds__(256) void k_bucket_scan(const int* __restrict__ gcnt,
                                                     int* __restrict__ bbase,
                                                     int* __restrict__ bcur, int NB) {
  __shared__ int sc[256];
  int tid = threadIdx.x;
  int v = (tid < NB) ? gcnt[tid] : 0;
  sc[tid] = v;
  __syncthreads();
  for (int off = 1; off < 256; off <<= 1) {
    int u = (tid >= off) ? sc[tid - off] : 0;
    __syncthreads();
    sc[tid] += u;
    __syncthreads();
  }
  int excl = sc[tid] - v;
  if (tid < NB) { bbase[tid] = excl; bcur[tid] = excl; }
  if (tid == 255) bbase[NB] = sc[255];
}

__global__ __launch_bounds__(256) void k_bucket_scatter(
    const int* __restrict__ src, const int* __restrict__ dst, int E,
    int* __restrict__ bcur, uint32_t* __restrict__ staged, int NB) {
  __shared__ int h[256];
  __shared__ int base[256];
  int tid = threadIdx.x;
  if (tid < NB) h[tid] = 0;
  __syncthreads();
  int cbase = blockIdx.x * CH;
  int cend = min(cbase + CH, E);
  uint32_t pay[16];
  int bk[16], rk[16];
#pragma unroll
  for (int k = 0; k < 16; ++k) {
    int i = cbase + tid + (k << 8);
    bool valid = i < cend;
    int d = valid ? dst[i] : 0;
    int s = valid ? src[i] : 0;
    int b = d >> BKSH;
    bk[k] = valid ? b : -1;
    rk[k] = valid ? atomicAdd(&h[b], 1) : 0;
    pay[k] = (uint32_t)s | ((uint32_t)(d & (BK - 1)) << 20);
  }
  __syncthreads();
  if (tid < NB && h[tid]) base[tid] = atomicAdd(&bcur[tid], h[tid]);
  __syncthreads();
#pragma unroll
  for (int k = 0; k < 16; ++k)
    if (bk[k] >= 0) staged[base[bk[k]] + rk[k]] = pay[k];
}

__global__ __launch_bounds__(256) void k_csr_final(
    const uint32_t* __restrict__ staged, const int* __restrict__ bbase,
    int* __restrict__ offs, int* __restrict__ counts, int* __restrict__ csr, int n) {
  __shared__ int nhist[BK];
  __shared__ int sc[BK];
  __shared__ int ncur[BK];
  __shared__ int csrloc[CAP];
  int b = blockIdx.x, tid = threadIdx.x;
  int bb = bbase[b], be = bbase[b + 1];
  int cnt = be - bb;
  for (int t = tid; t < BK; t += 256) nhist[t] = 0;
  __syncthreads();
  for (int k = tid; k < cnt; k += 256) atomicAdd(&nhist[staged[bb + k] >> 20], 1);
  __syncthreads();
  sc[tid] = nhist[tid];
  sc[tid + 256] = nhist[tid + 256];
  __syncthreads();
  for (int off = 1; off < BK; off <<= 1) {
    int a0 = (tid >= off) ? sc[tid - off] : 0;
    int a1 = (tid + 256 >= off) ? sc[tid + 256 - off] : 0;
    __syncthreads();
    sc[tid] += a0;
    sc[tid + 256] += a1;
    __syncthreads();
  }
  int node0 = b << BKSH;
  for (int t = tid; t < BK; t += 256) {
    int excl = sc[t] - nhist[t];
    int node = node0 + t;
    if (node < n) { counts[node] = nhist[t]; offs[node] = bb + excl; }
    ncur[t] = excl;
  }
  __syncthreads();
  for (int k = tid; k < cnt; k += 256) {
    uint32_t u = staged[bb + k];
    int dl = u >> 20;
    int s = (int)(u & 0xFFFFFu);
    int pos = atomicAdd(&ncur[dl], 1);
    if (pos < CAP) csrloc[pos] = s;
    else csr[bb + pos] = s;
  }
  __syncthreads();
  int lim = min(cnt, CAP);
  for (int k = tid; k < lim; k += 256) csr[bb + k] = csrloc[k];
}

// ---------------- fused GEMM + attention logits (H written as bf16) -------

template <int K, int R>
__global__ __launch_bounds__(256) void k_gemm_attn(
    const float* __restrict__ X, const float* __restrict__ W,
    const float* __restrict__ As, const float* __restrict__ Ad,
    uint16_t* __restrict__ H2, float* __restrict__ LS, float* __restrict__ LD, int n) {
  int lane = threadIdx.x & 63;
  int wave = threadIdx.x >> 6;
  int row0 = (blockIdx.x * 4 + wave) * R;
  if (row0 >= n) return;
  float acc[R];
#pragma unroll
  for (int r = 0; r < R; ++r) acc[r] = 0.f;

  for (int k0 = 0; k0 < K; k0 += 64) {
    float wreg[64];
#pragma unroll
    for (int kk = 0; kk < 64; ++kk) wreg[kk] = W[(size_t)(k0 + kk) * 64 + lane];
    float xv[R];
#pragma unroll
    for (int r = 0; r < R; ++r) {
      int row = row0 + r;
      if (row >= n) row = n - 1;                 // clamp (loads only)
      xv[r] = X[(size_t)row * K + k0 + lane];
    }
#pragma unroll
    for (int kk = 0; kk < 64; ++kk) {
#pragma unroll
      for (int r = 0; r < R; ++r)
        acc[r] = fmaf(bcast(xv[r], kk), wreg[kk], acc[r]);
    }
  }

  float as = As[lane], ad = Ad[lane];
#pragma unroll
  for (int r = 0; r < R; ++r) {
    int row = row0 + r;
    if (row >= n) break;
    __hip_bfloat16 hb = __float2bfloat16(acc[r]);    // RNE
    H2[((size_t)row << 6) | lane] = *(uint16_t*)&hb;
    float vs = acc[r] * as;
    float vd = acc[r] * ad;
#pragma unroll
    for (int off = 32; off; off >>= 1) {
      vs += __shfl_xor(vs, off);
      vd += __shfl_xor(vd, off);
    }
    if (lane == 0) { LS[row] = vs; LD[row] = vd; }
  }
}

// ---------------- per-node softmax aggregation (online, bf16 quad-gather) --
// One wave per node. Edge phase: 64 lanes compute e/exp in parallel.
// Gather phase: 4 groups of 16 lanes; group g serves edge jj+g of each
// 4-edge round; lane (g,q) loads ushort4 = features 4q..4q+3 of the row.
// Cross-group combine via shfl_xor(16), shfl_xor(32).

template <bool LAST>
__global__ __launch_bounds__(256) void k_aggregate(
    const uint16_t* __restrict__ H2, const float* __restrict__ LS, const float* __restrict__ LD,
    const int* __restrict__ csr, const int* __restrict__ offs, const int* __restrict__ counts,
    const float* __restrict__ b, float* __restrict__ Out, int n) {
  int lane = threadIdx.x & 63;
  int node = blockIdx.x * 4 + (threadIdx.x >> 6);
  if (node >= n) return;
  int q = lane & 15;        // feature quad: features 4q..4q+3
  int g = lane >> 4;        // edge group 0..3
  int start = offs[node];
  int deg = counts[node];
  float4 bb = ((const float4*)b)[q];
  float ldv = LD[node];
  float m = lrelu(LS[node] + ldv);                 // e_self (running max)
  float ssum_l = (lane == 0) ? 1.f : 0.f;

  // self contribution (w=1), only group 0 accumulates it
  ushort4 us = *(const ushort4*)&H2[((size_t)node << 6) + 4 * q];
  float wself = (g == 0) ? 1.f : 0.f;
  float acc0 = wself * bf2f(us.x);
  float acc1 = wself * bf2f(us.y);
  float acc2 = wself * bf2f(us.z);
  float acc3 = wself * bf2f(us.w);

  for (int c = 0; c < deg; c += 64) {
    int j = c + lane;
    bool valid = j < deg;
    int sidx = csr[start + (valid ? j : 0)];
    float e = valid ? lrelu(LS[sidx] + ldv) : -1e30f;
    float cm = e;
#pragma unroll
    for (int off = 32; off; off >>= 1) cm = fmaxf(cm, __shfl_xor(cm, off));
    if (cm > m) {
      float scale = __expf(m - cm);
      acc0 *= scale; acc1 *= scale; acc2 *= scale; acc3 *= scale;
      ssum_l *= scale;
      m = cm;
    }
    float w = valid ? __expf(e - m) : 0.f;         // invalid lanes: w = 0
    ssum_l += w;
    int nn = min(64, deg - c);
    int jj = 0;
    for (; jj + 16 <= nn; jj += 16) {              // 4 rounds of 4 edges
      float wg[4]; int sg[4];
#pragma unroll
      for (int t = 0; t < 4; ++t) {
        int idx = jj + 4 * t + g;
        wg[t] = __shfl(w, idx);
        sg[t] = __shfl(sidx, idx);
      }
      ushort4 u[4];
#pragma unroll
      for (int t = 0; t < 4; ++t)
        u[t] = *(const ushort4*)&H2[((size_t)sg[t] << 6) + 4 * q];
#pragma unroll
      for (int t = 0; t < 4; ++t) {
        acc0 = fmaf(wg[t], bf2f(u[t].x), acc0);
        acc1 = fmaf(wg[t], bf2f(u[t].y), acc1);
        acc2 = fmaf(wg[t], bf2f(u[t].z), acc2);
        acc3 = fmaf(wg[t], bf2f(u[t].w), acc3);
      }
    }
    for (; jj < nn; jj += 4) {                     // residue rounds
      int idx = min(jj + g, 63);                   // overflow lanes have w=0
      float wg = __shfl(w, idx);
      int sg = __shfl(sidx, idx);
      ushort4 u = *(const ushort4*)&H2[((size_t)sg << 6) + 4 * q];
      acc0 = fmaf(wg, bf2f(u.x), acc0);
      acc1 = fmaf(wg, bf2f(u.y), acc1);
      acc2 = fmaf(wg, bf2f(u.z), acc2);
      acc3 = fmaf(wg, bf2f(u.w), acc3);
    }
  }
  // combine the 4 edge-groups (every lane ends with the full sum)
  acc0 += __shfl_xor(acc0, 16); acc0 += __shfl_xor(acc0, 32);
  acc1 += __shfl_xor(acc1, 16); acc1 += __shfl_xor(acc1, 32);
  acc2 += __shfl_xor(acc2, 16); acc2 += __shfl_xor(acc2, 32);
  acc3 += __shfl_xor(acc3, 16); acc3 += __shfl_xor(acc3, 32);
  float ssum = ssum_l;
#pragma unroll
  for (int off = 32; off; off >>= 1) ssum += __shfl_xor(ssum, off);
  float inv = 1.f / ssum;
  float v0 = fmaxf(fmaf(acc0, inv, bb.x), 0.f);
  float v1 = fmaxf(fmaf(acc1, inv, bb.y), 0.f);
  float v2 = fmaxf(fmaf(acc2, inv, bb.z), 0.f);
  float v3 = fmaxf(fmaf(acc3, inv, bb.w), 0.f);
  if (LAST) {
    float mx = fmaxf(fmaxf(v0, v1), fmaxf(v2, v3));
#pragma unroll
    for (int off = 8; off; off >>= 1) mx = fmaxf(mx, __shfl_xor(mx, off));
    float ex = __expf(v0 - mx) + __expf(v1 - mx) + __expf(v2 - mx) + __expf(v3 - mx);
#pragma unroll
    for (int off = 8; off; off >>= 1) ex += __shfl_xor(ex, off);
    float lse = mx + logf(ex);
    v0 -= lse; v1 -= lse; v2 -= lse; v3 -= lse;
  }
  if (g == 0)
    ((float4*)(Out + ((size_t)node << 6)))[q] = make_float4(v0, v1, v2, v3);
}

// ---------------- launcher ----------------

extern "C" void kernel_launch(void* const* d_in, const int* in_sizes, int n_in,
                              void* d_out, int out_size, void* d_ws, size_t ws_size,
                              hipStream_t stream) {
  const float* x = (const float*)d_in[0];
  const int* ei = (const int*)d_in[1];
  const int N = in_sizes[0] / IN_DIM;       // 100000
  const int E = in_sizes[1] / 2;            // 1600000
  const int* src = ei;
  const int* dst = ei + E;
  const int NB = (N + BK - 1) >> BKSH;      // 196

  const float *W[6], *As[6], *Ad[6], *Bb[6];
  for (int i = 0; i < 6; ++i) {
    W[i]  = (const float*)d_in[3 + 4 * i];
    As[i] = (const float*)d_in[4 + 4 * i];
    Ad[i] = (const float*)d_in[5 + 4 * i];
    Bb[i] = (const float*)d_in[6 + 4 * i];
  }

  char* p = (char*)d_ws;
  auto alloc = [&](size_t bytes) -> void* {
    void* r = (void*)p;
    p += (bytes + 255) & ~(size_t)255;
    return r;
  };
  int* counts  = (int*)alloc((size_t)N * 4);
  int* offs    = (int*)alloc((size_t)N * 4);
  int* gcnt    = (int*)alloc((size_t)NB * 4);
  int* bbase   = (int*)alloc((size_t)(NB + 1) * 4);
  int* bcur    = (int*)alloc((size_t)NB * 4);
  int* csr     = (int*)alloc((size_t)E * 4);
  float* ls    = (float*)alloc((size_t)N * 4);
  float* ld    = (float*)alloc((size_t)N * 4);
  uint16_t* h2 = (uint16_t*)alloc((size_t)N * HID * 2);
  float* F0    = (float*)alloc((size_t)N * HID * 4);
  float* F1    = (float*)d_out;
  uint32_t* staged = (uint32_t*)F0;          // alias: dead before first aggregate

  // ---- CSR build ----
  int NC = (E + CH - 1) / CH;
  hipMemsetAsync(gcnt, 0, (size_t)NB * 4, stream);
  k_bucket_hist<<<NC, 256, 0, stream>>>(dst, E, gcnt, NB);
  k_bucket_scan<<<1, 256, 0, stream>>>(gcnt, bbase, bcur, NB);
  k_bucket_scatter<<<NC, 256, 0, stream>>>(src, dst, E, bcur, staged, NB);
  k_csr_final<<<NB, 256, 0, stream>>>(staged, bbase, offs, counts, csr, N);

  // ---- 6 GAT layers ----
  const int R = 8;
  int gemm_grid = (N + 4 * R - 1) / (4 * R);    // 3125
  int node_grid = (N + 3) / 4;                  // 25000
  const float* fin = x;
  float* fbuf[2] = {F0, F1};
  for (int L = 0; L < 6; ++L) {
    if (L == 0)
      k_gemm_attn<IN_DIM, R><<<gemm_grid, 256, 0, stream>>>(fin, W[L], As[L], Ad[L],
                                                            h2, ls, ld, N);
    else
      k_gemm_attn<HID, R><<<gemm_grid, 256, 0, stream>>>(fin, W[L], As[L], Ad[L],
                                                         h2, ls, ld, N);
    float* fout = fbuf[L & 1];
    if (L == 5)
      k_aggregate<true><<<node_grid, 256, 0, stream>>>(h2, ls, ld, csr, offs, counts,
                                                       Bb[L], fout, N);
    else
      k_aggregate<false><<<node_grid, 256, 0, stream>>>(h2, ls, ld, csr, offs, counts,
                                                        Bb[L], fout, N);
    fin = fout;
  }
}